// Round 1
// baseline (1478.131 us; speedup 1.0000x reference)
//
#include <hip/hip_runtime.h>
#include <hip/hip_bf16.h>

// GCNBlock: h = x@W ; GCN aggregate with sym norm + self loops ; graph-LayerNorm ; PReLU
// N=50000, E=800000, F=256 (derived from in_sizes at launch)

#define F 256
#define EPSV 1e-5f

typedef __attribute__((ext_vector_type(8))) short short8;
typedef __attribute__((ext_vector_type(4))) float f32x4;

__device__ __forceinline__ short f2bf(float f) {
  union { float f; unsigned u; } v; v.f = f;
  unsigned r = v.u + 0x7fffu + ((v.u >> 16) & 1u);  // RNE
  return (short)(r >> 16);
}

// ---- CSR build -------------------------------------------------------------

__global__ void count_deg(const int* __restrict__ dst, int* __restrict__ deg_cnt, int E) {
  int e = blockIdx.x * blockDim.x + threadIdx.x;
  if (e < E) atomicAdd(&deg_cnt[dst[e]], 1);
}

__global__ void compute_dinv(const int* __restrict__ deg_cnt, float* __restrict__ dinv, int N) {
  int i = blockIdx.x * blockDim.x + threadIdx.x;
  if (i < N) dinv[i] = rsqrtf((float)(deg_cnt[i] + 1));  // +1 self loop
}

__global__ void block_sums(const int* __restrict__ deg_cnt, int* __restrict__ bsum, int N) {
  __shared__ int s[256];
  int t = threadIdx.x;
  int i = blockIdx.x * 256 + t;
  s[t] = (i < N) ? deg_cnt[i] : 0;
  __syncthreads();
  for (int off = 128; off > 0; off >>= 1) {
    if (t < off) s[t] += s[t + off];
    __syncthreads();
  }
  if (t == 0) bsum[blockIdx.x] = s[0];
}

// exclusive scan of <=256 block sums, single block
__global__ void scan_bsums(const int* __restrict__ bsum, int* __restrict__ boff, int nb) {
  __shared__ int s[256];
  int t = threadIdx.x;
  int v = (t < nb) ? bsum[t] : 0;
  s[t] = v;
  __syncthreads();
  for (int off = 1; off < 256; off <<= 1) {
    int x = (t >= off) ? s[t - off] : 0;
    __syncthreads();
    s[t] += x;
    __syncthreads();
  }
  if (t < nb) boff[t] = s[t] - v;  // exclusive
}

__global__ void write_csr(const int* __restrict__ deg_cnt, const int* __restrict__ boff,
                          int* __restrict__ csr_ptr, int N, int E) {
  __shared__ int s[256];
  int t = threadIdx.x;
  int i = blockIdx.x * 256 + t;
  int v = (i < N) ? deg_cnt[i] : 0;
  s[t] = v;
  __syncthreads();
  for (int off = 1; off < 256; off <<= 1) {
    int x = (t >= off) ? s[t - off] : 0;
    __syncthreads();
    s[t] += x;
    __syncthreads();
  }
  if (i < N) csr_ptr[i] = boff[blockIdx.x] + s[t] - v;
  if (i == 0) csr_ptr[N] = E;
}

__global__ void fill_csr(const int* __restrict__ src, const int* __restrict__ dst,
                         const int* __restrict__ csr_ptr, int* __restrict__ csr_fill,
                         int* __restrict__ csr_src, int E) {
  int e = blockIdx.x * blockDim.x + threadIdx.x;
  if (e < E) {
    int d = dst[e];
    int pos = csr_ptr[d] + atomicAdd(&csr_fill[d], 1);
    csr_src[pos] = src[e];
  }
}

// ---- GEMM h = x @ W (bf16 MFMA) -------------------------------------------

// Repack W (fp32 [K=256][N=256]) into bf16 B-fragment layout:
// Wb[((t*8 + kc)*64 + lane)*8 + j] = W[kc*32 + (lane>>4)*8 + j][t*16 + (lane&15)]
__global__ void prep_W(const float* __restrict__ W, short* __restrict__ Wb) {
  int gid = blockIdx.x * blockDim.x + threadIdx.x;  // 65536 total
  int j = gid & 7;
  int lane = (gid >> 3) & 63;
  int kc = (gid >> 9) & 7;
  int t = gid >> 12;
  int k = kc * 32 + (lane >> 4) * 8 + j;
  int n = t * 16 + (lane & 15);
  Wb[gid] = f2bf(W[k * 256 + n]);
}

// block = 256 thr = 4 waves; block handles 16 rows x 256 cols; wave w -> cols w*64..w*64+63
__global__ void gemm_xw(const float* __restrict__ x, const short* __restrict__ Wb,
                        float* __restrict__ h, int N) {
  int lane = threadIdx.x & 63;
  int wave = threadIdx.x >> 6;
  int m0 = blockIdx.x * 16;
  int q = lane >> 4;

  int row = m0 + (lane & 15);
  int rowc = row < N ? row : N - 1;

  f32x4 acc[4] = {{0,0,0,0},{0,0,0,0},{0,0,0,0},{0,0,0,0}};

  for (int kc = 0; kc < 8; ++kc) {
    int koff = kc * 32 + q * 8;
    const float4* xp = (const float4*)(x + (size_t)rowc * F + koff);
    float4 a0 = xp[0];
    float4 a1 = xp[1];
    short8 a;
    a[0] = f2bf(a0.x); a[1] = f2bf(a0.y); a[2] = f2bf(a0.z); a[3] = f2bf(a0.w);
    a[4] = f2bf(a1.x); a[5] = f2bf(a1.y); a[6] = f2bf(a1.z); a[7] = f2bf(a1.w);
#pragma unroll
    for (int tt = 0; tt < 4; ++tt) {
      const short8 b = *(const short8*)(Wb + (((wave * 4 + tt) * 8 + kc) * 64 + lane) * 8);
      acc[tt] = __builtin_amdgcn_mfma_f32_16x16x32_bf16(a, b, acc[tt], 0, 0, 0);
    }
  }

  int crow = q * 4;
  int ccol = lane & 15;
#pragma unroll
  for (int tt = 0; tt < 4; ++tt) {
#pragma unroll
    for (int rr = 0; rr < 4; ++rr) {
      int orow = m0 + crow + rr;
      if (orow < N) h[(size_t)orow * F + wave * 64 + tt * 16 + ccol] = acc[tt][rr];
    }
  }
}

// ---- Aggregation + bias + global-stat partials ----------------------------

__global__ void aggregate(const float* __restrict__ h, const int* __restrict__ csr_ptr,
                          const int* __restrict__ csr_src, const float* __restrict__ dinv,
                          const float* __restrict__ conv_bias, float* __restrict__ out,
                          double* __restrict__ sums, int N) {
  int i = blockIdx.x;
  int c = threadIdx.x;
  float di = dinv[i];
  float acc = h[(size_t)i * F + c] * di * di;  // self loop
  int b0 = csr_ptr[i], b1 = csr_ptr[i + 1];
  for (int e = b0; e < b1; ++e) {
    int s = csr_src[e];
    float w = dinv[s] * di;
    acc += h[(size_t)s * F + c] * w;
  }
  acc += conv_bias[c];
  out[(size_t)i * F + c] = acc;

  __shared__ float r1[256];
  __shared__ float r2[256];
  r1[c] = acc;
  r2[c] = acc * acc;
  __syncthreads();
  for (int off = 128; off > 0; off >>= 1) {
    if (c < off) { r1[c] += r1[c + off]; r2[c] += r2[c + off]; }
    __syncthreads();
  }
  if (c == 0) {
    atomicAdd(&sums[0], (double)r1[0]);
    atomicAdd(&sums[1], (double)r2[0]);
  }
}

__global__ void finalize_stats(const double* __restrict__ sums, float* __restrict__ stats,
                               double cnt) {
  double mu = sums[0] / cnt;
  double var = sums[1] / cnt - mu * mu;
  if (var < 0) var = 0;
  double sd = sqrt(var);
  stats[0] = (float)mu;
  stats[1] = (float)(1.0 / (sd + (double)EPSV));
}

__global__ void norm_prelu(float4* __restrict__ out, const float* __restrict__ stats,
                           const float* __restrict__ lw, const float* __restrict__ lb,
                           const float* __restrict__ pa, int n4) {
  int i = blockIdx.x * blockDim.x + threadIdx.x;
  if (i >= n4) return;
  float mu = stats[0];
  float inv = stats[1];
  float a = pa[0];
  int c4 = (i & 63) * 4;  // 256 cols / 4 per float4
  float4 w = *(const float4*)(lw + c4);
  float4 b = *(const float4*)(lb + c4);
  float4 v = out[i];
  float y0 = (v.x - mu) * inv * w.x + b.x;
  float y1 = (v.y - mu) * inv * w.y + b.y;
  float y2 = (v.z - mu) * inv * w.z + b.z;
  float y3 = (v.w - mu) * inv * w.w + b.w;
  v.x = y0 >= 0.f ? y0 : a * y0;
  v.y = y1 >= 0.f ? y1 : a * y1;
  v.z = y2 >= 0.f ? y2 : a * y2;
  v.w = y3 >= 0.f ? y3 : a * y3;
  out[i] = v;
}

// ---- launch ---------------------------------------------------------------

extern "C" void kernel_launch(void* const* d_in, const int* in_sizes, int n_in,
                              void* d_out, int out_size, void* d_ws, size_t ws_size,
                              hipStream_t stream) {
  const float* x = (const float*)d_in[0];
  const int* eidx = (const int*)d_in[1];
  // d_in[2] = batch (unused; all zeros)
  const float* W = (const float*)d_in[3];
  const float* conv_bias = (const float*)d_in[4];
  const float* ln_w = (const float*)d_in[5];
  const float* ln_b = (const float*)d_in[6];
  const float* prelu_a = (const float*)d_in[7];
  float* out = (float*)d_out;

  int N = in_sizes[0] / F;
  int E = in_sizes[1] / 2;
  const int* src = eidx;
  const int* dst = eidx + E;

  // workspace carve (256B aligned)
  char* p = (char*)d_ws;
  auto carve = [&](size_t bytes) { char* r = p; p += (bytes + 255) & ~(size_t)255; return r; };
  float* h       = (float*)carve((size_t)N * F * sizeof(float));
  short* Wb      = (short*)carve((size_t)F * F * sizeof(short));
  int* deg_cnt   = (int*)carve((size_t)N * sizeof(int));
  float* dinv    = (float*)carve((size_t)N * sizeof(float));
  int* csr_ptr   = (int*)carve((size_t)(N + 1) * sizeof(int));
  int* csr_fill  = (int*)carve((size_t)N * sizeof(int));
  int* csr_src   = (int*)carve((size_t)E * sizeof(int));
  int NB = (N + 255) / 256;
  int* bsum      = (int*)carve((size_t)NB * sizeof(int));
  int* boff      = (int*)carve((size_t)NB * sizeof(int));
  double* sums   = (double*)carve(2 * sizeof(double));
  float* stats   = (float*)carve(2 * sizeof(float));

  hipMemsetAsync(deg_cnt, 0, (size_t)N * sizeof(int), stream);
  hipMemsetAsync(csr_fill, 0, (size_t)N * sizeof(int), stream);
  hipMemsetAsync(sums, 0, 2 * sizeof(double), stream);

  int eb = (E + 255) / 256;
  count_deg<<<eb, 256, 0, stream>>>(dst, deg_cnt, E);
  compute_dinv<<<NB, 256, 0, stream>>>(deg_cnt, dinv, N);
  block_sums<<<NB, 256, 0, stream>>>(deg_cnt, bsum, N);
  scan_bsums<<<1, 256, 0, stream>>>(bsum, boff, NB);
  write_csr<<<NB, 256, 0, stream>>>(deg_cnt, boff, csr_ptr, N, E);
  fill_csr<<<eb, 256, 0, stream>>>(src, dst, csr_ptr, csr_fill, csr_src, E);

  prep_W<<<(F * F) / 256, 256, 0, stream>>>(W, Wb);
  gemm_xw<<<(N + 15) / 16, 256, 0, stream>>>(x, Wb, h, N);

  aggregate<<<N, 256, 0, stream>>>(h, csr_ptr, csr_src, dinv, conv_bias, out, sums, N);
  finalize_stats<<<1, 1, 0, stream>>>(sums, stats, (double)N * (double)F);
  int n4 = N * (F / 4);
  norm_prelu<<<(n4 + 255) / 256, 256, 0, stream>>>((float4*)out, stats, ln_w, ln_b, prelu_a, n4);
}

// Round 2
// 587.154 us; speedup vs baseline: 2.5174x; 2.5174x over previous
//
#include <hip/hip_runtime.h>
#include <hip/hip_bf16.h>

// GCNBlock: h' = (x@W)*dinv ; gather-aggregate ; graph-LayerNorm ; PReLU
// N=50000, E=800000, F=256

#define F 256
#define EPSV 1e-5f

typedef __attribute__((ext_vector_type(8))) short short8;
typedef __attribute__((ext_vector_type(4))) float f32x4;

__device__ __forceinline__ short f2bf(float f) {
  union { float f; unsigned u; } v; v.f = f;
  unsigned r = v.u + 0x7fffu + ((v.u >> 16) & 1u);  // RNE
  return (short)(r >> 16);
}

// ---- CSR build -------------------------------------------------------------

__global__ void count_deg(const int* __restrict__ dst, int* __restrict__ deg_cnt, int E) {
  int e = blockIdx.x * blockDim.x + threadIdx.x;
  if (e < E) atomicAdd(&deg_cnt[dst[e]], 1);
}

__global__ void compute_dinv(const int* __restrict__ deg_cnt, float* __restrict__ dinv, int N) {
  int i = blockIdx.x * blockDim.x + threadIdx.x;
  if (i < N) dinv[i] = rsqrtf((float)(deg_cnt[i] + 1));  // +1 self loop
}

__global__ void block_sums(const int* __restrict__ deg_cnt, int* __restrict__ bsum, int N) {
  __shared__ int s[256];
  int t = threadIdx.x;
  int i = blockIdx.x * 256 + t;
  s[t] = (i < N) ? deg_cnt[i] : 0;
  __syncthreads();
  for (int off = 128; off > 0; off >>= 1) {
    if (t < off) s[t] += s[t + off];
    __syncthreads();
  }
  if (t == 0) bsum[blockIdx.x] = s[0];
}

__global__ void scan_bsums(const int* __restrict__ bsum, int* __restrict__ boff, int nb) {
  __shared__ int s[256];
  int t = threadIdx.x;
  int v = (t < nb) ? bsum[t] : 0;
  s[t] = v;
  __syncthreads();
  for (int off = 1; off < 256; off <<= 1) {
    int x = (t >= off) ? s[t - off] : 0;
    __syncthreads();
    s[t] += x;
    __syncthreads();
  }
  if (t < nb) boff[t] = s[t] - v;  // exclusive
}

__global__ void write_csr(const int* __restrict__ deg_cnt, const int* __restrict__ boff,
                          int* __restrict__ csr_ptr, int N, int E) {
  __shared__ int s[256];
  int t = threadIdx.x;
  int i = blockIdx.x * 256 + t;
  int v = (i < N) ? deg_cnt[i] : 0;
  s[t] = v;
  __syncthreads();
  for (int off = 1; off < 256; off <<= 1) {
    int x = (t >= off) ? s[t - off] : 0;
    __syncthreads();
    s[t] += x;
    __syncthreads();
  }
  if (i < N) csr_ptr[i] = boff[blockIdx.x] + s[t] - v;
  if (i == 0) csr_ptr[N] = E;
}

__global__ void fill_csr(const int* __restrict__ src, const int* __restrict__ dst,
                         const int* __restrict__ csr_ptr, int* __restrict__ csr_fill,
                         int* __restrict__ csr_src, int E) {
  int e = blockIdx.x * blockDim.x + threadIdx.x;
  if (e < E) {
    int d = dst[e];
    int pos = csr_ptr[d] + atomicAdd(&csr_fill[d], 1);
    csr_src[pos] = src[e];
  }
}

// ---- GEMM h' = (x @ W) * dinv[row]  (bf16 MFMA) ----------------------------

__global__ void prep_W(const float* __restrict__ W, short* __restrict__ Wb) {
  int gid = blockIdx.x * blockDim.x + threadIdx.x;  // 65536 total
  int j = gid & 7;
  int lane = (gid >> 3) & 63;
  int kc = (gid >> 9) & 7;
  int t = gid >> 12;
  int k = kc * 32 + (lane >> 4) * 8 + j;
  int n = t * 16 + (lane & 15);
  Wb[gid] = f2bf(W[k * 256 + n]);
}

// block = 256 thr = 4 waves; block handles 16 rows x 256 cols; wave w -> cols w*64..
__global__ void gemm_xw(const float* __restrict__ x, const short* __restrict__ Wb,
                        const float* __restrict__ dinv, float* __restrict__ h, int N) {
  int lane = threadIdx.x & 63;
  int wave = threadIdx.x >> 6;
  int m0 = blockIdx.x * 16;
  int q = lane >> 4;

  int row = m0 + (lane & 15);
  int rowc = row < N ? row : N - 1;

  f32x4 acc[4] = {{0,0,0,0},{0,0,0,0},{0,0,0,0},{0,0,0,0}};

  for (int kc = 0; kc < 8; ++kc) {
    int koff = kc * 32 + q * 8;
    const float4* xp = (const float4*)(x + (size_t)rowc * F + koff);
    float4 a0 = xp[0];
    float4 a1 = xp[1];
    short8 a;
    a[0] = f2bf(a0.x); a[1] = f2bf(a0.y); a[2] = f2bf(a0.z); a[3] = f2bf(a0.w);
    a[4] = f2bf(a1.x); a[5] = f2bf(a1.y); a[6] = f2bf(a1.z); a[7] = f2bf(a1.w);
#pragma unroll
    for (int tt = 0; tt < 4; ++tt) {
      const short8 b = *(const short8*)(Wb + (((wave * 4 + tt) * 8 + kc) * 64 + lane) * 8);
      acc[tt] = __builtin_amdgcn_mfma_f32_16x16x32_bf16(a, b, acc[tt], 0, 0, 0);
    }
  }

  int crow = q * 4;
  int ccol = lane & 15;
  float dv[4];
#pragma unroll
  for (int rr = 0; rr < 4; ++rr) {
    int orow = m0 + crow + rr;
    dv[rr] = (orow < N) ? dinv[orow] : 0.f;
  }
#pragma unroll
  for (int tt = 0; tt < 4; ++tt) {
#pragma unroll
    for (int rr = 0; rr < 4; ++rr) {
      int orow = m0 + crow + rr;
      if (orow < N) h[(size_t)orow * F + wave * 64 + tt * 16 + ccol] = acc[tt][rr] * dv[rr];
    }
  }
}

// ---- Aggregation: one row per wave, 8-way unrolled gather ------------------

__global__ void aggregate(const float4* __restrict__ hp, const int* __restrict__ csr_ptr,
                          const int* __restrict__ csr_src, const float* __restrict__ dinv,
                          const float* __restrict__ conv_bias, float4* __restrict__ out,
                          double* __restrict__ sums, int N) {
  int wave = threadIdx.x >> 6;
  int lane = threadIdx.x & 63;
  int row = blockIdx.x * 4 + wave;
  float s1 = 0.f, s2 = 0.f;

  if (row < N) {
    float di = dinv[row];
    int b0 = csr_ptr[row], b1 = csr_ptr[row + 1];
    float4 acc = hp[(size_t)row * 64 + lane];  // self-loop contribution (h' = h*dinv)

    for (int e = b0; e < b1; e += 8) {
      int idx[8];
#pragma unroll
      for (int j = 0; j < 8; ++j) {
        int ee = e + j;
        idx[j] = csr_src[ee < b1 ? ee : b1 - 1];
      }
      float4 v[8];
#pragma unroll
      for (int j = 0; j < 8; ++j) v[j] = hp[(size_t)idx[j] * 64 + lane];
#pragma unroll
      for (int j = 0; j < 8; ++j) {
        float m = (e + j < b1) ? 1.f : 0.f;
        acc.x = fmaf(v[j].x, m, acc.x);
        acc.y = fmaf(v[j].y, m, acc.y);
        acc.z = fmaf(v[j].z, m, acc.z);
        acc.w = fmaf(v[j].w, m, acc.w);
      }
    }

    float4 b = *(const float4*)(conv_bias + lane * 4);
    acc.x = fmaf(acc.x, di, b.x);
    acc.y = fmaf(acc.y, di, b.y);
    acc.z = fmaf(acc.z, di, b.z);
    acc.w = fmaf(acc.w, di, b.w);
    out[(size_t)row * 64 + lane] = acc;
    s1 = acc.x + acc.y + acc.z + acc.w;
    s2 = acc.x * acc.x + acc.y * acc.y + acc.z * acc.z + acc.w * acc.w;
  }

  __shared__ float r1[256];
  __shared__ float r2[256];
  int t = threadIdx.x;
  r1[t] = s1;
  r2[t] = s2;
  __syncthreads();
  for (int off = 128; off > 0; off >>= 1) {
    if (t < off) { r1[t] += r1[t + off]; r2[t] += r2[t + off]; }
    __syncthreads();
  }
  if (t == 0) {
    atomicAdd(&sums[0], (double)r1[0]);
    atomicAdd(&sums[1], (double)r2[0]);
  }
}

__global__ void finalize_stats(const double* __restrict__ sums, float* __restrict__ stats,
                               double cnt) {
  double mu = sums[0] / cnt;
  double var = sums[1] / cnt - mu * mu;
  if (var < 0) var = 0;
  double sd = sqrt(var);
  stats[0] = (float)mu;
  stats[1] = (float)(1.0 / (sd + (double)EPSV));
}

__global__ void norm_prelu(float4* __restrict__ out, const float* __restrict__ stats,
                           const float* __restrict__ lw, const float* __restrict__ lb,
                           const float* __restrict__ pa, int n4) {
  int i = blockIdx.x * blockDim.x + threadIdx.x;
  if (i >= n4) return;
  float mu = stats[0];
  float inv = stats[1];
  float a = pa[0];
  int c4 = (i & 63) * 4;
  float4 w = *(const float4*)(lw + c4);
  float4 b = *(const float4*)(lb + c4);
  float4 v = out[i];
  float y0 = (v.x - mu) * inv * w.x + b.x;
  float y1 = (v.y - mu) * inv * w.y + b.y;
  float y2 = (v.z - mu) * inv * w.z + b.z;
  float y3 = (v.w - mu) * inv * w.w + b.w;
  v.x = y0 >= 0.f ? y0 : a * y0;
  v.y = y1 >= 0.f ? y1 : a * y1;
  v.z = y2 >= 0.f ? y2 : a * y2;
  v.w = y3 >= 0.f ? y3 : a * y3;
  out[i] = v;
}

// ---- launch ---------------------------------------------------------------

extern "C" void kernel_launch(void* const* d_in, const int* in_sizes, int n_in,
                              void* d_out, int out_size, void* d_ws, size_t ws_size,
                              hipStream_t stream) {
  const float* x = (const float*)d_in[0];
  const int* eidx = (const int*)d_in[1];
  const float* W = (const float*)d_in[3];
  const float* conv_bias = (const float*)d_in[4];
  const float* ln_w = (const float*)d_in[5];
  const float* ln_b = (const float*)d_in[6];
  const float* prelu_a = (const float*)d_in[7];
  float* out = (float*)d_out;

  int N = in_sizes[0] / F;
  int E = in_sizes[1] / 2;
  const int* src = eidx;
  const int* dst = eidx + E;

  char* p = (char*)d_ws;
  auto carve = [&](size_t bytes) { char* r = p; p += (bytes + 255) & ~(size_t)255; return r; };
  float* h       = (float*)carve((size_t)N * F * sizeof(float));
  short* Wb      = (short*)carve((size_t)F * F * sizeof(short));
  int* deg_cnt   = (int*)carve((size_t)N * sizeof(int));
  float* dinv    = (float*)carve((size_t)N * sizeof(float));
  int* csr_ptr   = (int*)carve((size_t)(N + 1) * sizeof(int));
  int* csr_fill  = (int*)carve((size_t)N * sizeof(int));
  int* csr_src   = (int*)carve((size_t)E * sizeof(int));
  int NB = (N + 255) / 256;
  int* bsum      = (int*)carve((size_t)NB * sizeof(int));
  int* boff      = (int*)carve((size_t)NB * sizeof(int));
  double* sums   = (double*)carve(2 * sizeof(double));
  float* stats   = (float*)carve(2 * sizeof(float));

  hipMemsetAsync(deg_cnt, 0, (size_t)N * sizeof(int), stream);
  hipMemsetAsync(csr_fill, 0, (size_t)N * sizeof(int), stream);
  hipMemsetAsync(sums, 0, 2 * sizeof(double), stream);

  int eb = (E + 255) / 256;
  count_deg<<<eb, 256, 0, stream>>>(dst, deg_cnt, E);
  compute_dinv<<<NB, 256, 0, stream>>>(deg_cnt, dinv, N);
  block_sums<<<NB, 256, 0, stream>>>(deg_cnt, bsum, N);
  scan_bsums<<<1, 256, 0, stream>>>(bsum, boff, NB);
  write_csr<<<NB, 256, 0, stream>>>(deg_cnt, boff, csr_ptr, N, E);
  fill_csr<<<eb, 256, 0, stream>>>(src, dst, csr_ptr, csr_fill, csr_src, E);

  prep_W<<<(F * F) / 256, 256, 0, stream>>>(W, Wb);
  gemm_xw<<<(N + 15) / 16, 256, 0, stream>>>(x, Wb, dinv, h, N);

  aggregate<<<(N + 3) / 4, 256, 0, stream>>>((const float4*)h, csr_ptr, csr_src, dinv,
                                             conv_bias, (float4*)out, sums, N);
  finalize_stats<<<1, 1, 0, stream>>>(sums, stats, (double)N * (double)F);
  int n4 = N * (F / 4);
  norm_prelu<<<(n4 + 255) / 256, 256, 0, stream>>>((float4*)out, stats, ln_w, ln_b, prelu_a, n4);
}

// Round 3
// 569.421 us; speedup vs baseline: 2.5958x; 1.0311x over previous
//
#include <hip/hip_runtime.h>
#include <hip/hip_bf16.h>

// GCNBlock: h' = (x@W)*dinv stored bf16 ; gather-aggregate ; graph-LayerNorm ; PReLU
// N=50000, E=800000, F=256

#define F 256
#define EPSV 1e-5f

typedef __attribute__((ext_vector_type(8))) short short8;
typedef __attribute__((ext_vector_type(4))) float f32x4;

__device__ __forceinline__ unsigned short f2bf(float f) {
  union { float f; unsigned u; } v; v.f = f;
  unsigned r = v.u + 0x7fffu + ((v.u >> 16) & 1u);  // RNE
  return (unsigned short)(r >> 16);
}

__device__ __forceinline__ float bf2f(unsigned short u) {
  union { unsigned u; float f; } v; v.u = ((unsigned)u) << 16; return v.f;
}

// ---- CSR build -------------------------------------------------------------

__global__ void count_deg(const int* __restrict__ dst, int* __restrict__ deg_cnt, int E) {
  int e = blockIdx.x * blockDim.x + threadIdx.x;
  if (e < E) atomicAdd(&deg_cnt[dst[e]], 1);
}

__global__ void compute_dinv(const int* __restrict__ deg_cnt, float* __restrict__ dinv, int N) {
  int i = blockIdx.x * blockDim.x + threadIdx.x;
  if (i < N) dinv[i] = rsqrtf((float)(deg_cnt[i] + 1));  // +1 self loop
}

__global__ void block_sums(const int* __restrict__ deg_cnt, int* __restrict__ bsum, int N) {
  __shared__ int s[256];
  int t = threadIdx.x;
  int i = blockIdx.x * 256 + t;
  s[t] = (i < N) ? deg_cnt[i] : 0;
  __syncthreads();
  for (int off = 128; off > 0; off >>= 1) {
    if (t < off) s[t] += s[t + off];
    __syncthreads();
  }
  if (t == 0) bsum[blockIdx.x] = s[0];
}

__global__ void scan_bsums(const int* __restrict__ bsum, int* __restrict__ boff, int nb) {
  __shared__ int s[256];
  int t = threadIdx.x;
  int v = (t < nb) ? bsum[t] : 0;
  s[t] = v;
  __syncthreads();
  for (int off = 1; off < 256; off <<= 1) {
    int x = (t >= off) ? s[t - off] : 0;
    __syncthreads();
    s[t] += x;
    __syncthreads();
  }
  if (t < nb) boff[t] = s[t] - v;  // exclusive
}

__global__ void write_csr(const int* __restrict__ deg_cnt, const int* __restrict__ boff,
                          int* __restrict__ csr_ptr, int N, int E) {
  __shared__ int s[256];
  int t = threadIdx.x;
  int i = blockIdx.x * 256 + t;
  int v = (i < N) ? deg_cnt[i] : 0;
  s[t] = v;
  __syncthreads();
  for (int off = 1; off < 256; off <<= 1) {
    int x = (t >= off) ? s[t - off] : 0;
    __syncthreads();
    s[t] += x;
    __syncthreads();
  }
  if (i < N) csr_ptr[i] = boff[blockIdx.x] + s[t] - v;
  if (i == 0) csr_ptr[N] = E;
}

__global__ void fill_csr(const int* __restrict__ src, const int* __restrict__ dst,
                         const int* __restrict__ csr_ptr, int* __restrict__ csr_fill,
                         int* __restrict__ csr_src, int E) {
  int e = blockIdx.x * blockDim.x + threadIdx.x;
  if (e < E) {
    int d = dst[e];
    int pos = csr_ptr[d] + atomicAdd(&csr_fill[d], 1);
    csr_src[pos] = src[e];
  }
}

// ---- GEMM h' = (x @ W) * dinv[row], stored bf16 (MFMA) ---------------------

__global__ void prep_W(const float* __restrict__ W, unsigned short* __restrict__ Wb) {
  int gid = blockIdx.x * blockDim.x + threadIdx.x;  // 65536 total
  int j = gid & 7;
  int lane = (gid >> 3) & 63;
  int kc = (gid >> 9) & 7;
  int t = gid >> 12;
  int k = kc * 32 + (lane >> 4) * 8 + j;
  int n = t * 16 + (lane & 15);
  Wb[gid] = f2bf(W[k * 256 + n]);
}

// block = 256 thr = 4 waves; block handles 16 rows x 256 cols; wave w -> cols w*64..
__global__ void gemm_xw(const float* __restrict__ x, const unsigned short* __restrict__ Wb,
                        const float* __restrict__ dinv, ushort4* __restrict__ hb, int N) {
  int lane = threadIdx.x & 63;
  int wave = threadIdx.x >> 6;
  int m0 = blockIdx.x * 16;
  int q = lane >> 4;

  int row = m0 + (lane & 15);
  int rowc = row < N ? row : N - 1;

  f32x4 acc[4] = {{0,0,0,0},{0,0,0,0},{0,0,0,0},{0,0,0,0}};

  for (int kc = 0; kc < 8; ++kc) {
    int koff = kc * 32 + q * 8;
    const float4* xp = (const float4*)(x + (size_t)rowc * F + koff);
    float4 a0 = xp[0];
    float4 a1 = xp[1];
    short8 a;
    a[0] = f2bf(a0.x); a[1] = f2bf(a0.y); a[2] = f2bf(a0.z); a[3] = f2bf(a0.w);
    a[4] = f2bf(a1.x); a[5] = f2bf(a1.y); a[6] = f2bf(a1.z); a[7] = f2bf(a1.w);
#pragma unroll
    for (int tt = 0; tt < 4; ++tt) {
      const short8 b = *(const short8*)(Wb + (((wave * 4 + tt) * 8 + kc) * 64 + lane) * 8);
      acc[tt] = __builtin_amdgcn_mfma_f32_16x16x32_bf16(a, b, acc[tt], 0, 0, 0);
    }
  }

  // scale by dinv[row] and repack via LDS to coalesced bf16 stores
  __shared__ unsigned short lds[16][264];  // +8 pad breaks bank alias
  int crow = q * 4;
  int ccol = lane & 15;
#pragma unroll
  for (int rr = 0; rr < 4; ++rr) {
    int orow = m0 + crow + rr;
    float dv = (orow < N) ? dinv[orow] : 0.f;
#pragma unroll
    for (int tt = 0; tt < 4; ++tt) {
      lds[crow + rr][wave * 64 + tt * 16 + ccol] = f2bf(acc[tt][rr] * dv);
    }
  }
  __syncthreads();
  int t = threadIdx.x;
  int lrow = t >> 4;
  int grow = m0 + lrow;
  if (grow < N) {
#pragma unroll
    for (int it = 0; it < 4; ++it) {
      int c4 = (t & 15) + 16 * it;  // ushort4 index 0..63
      ushort4 u = *(const ushort4*)&lds[lrow][c4 * 4];
      hb[(size_t)grow * 64 + c4] = u;
    }
  }
}

// ---- Aggregation: one row per wave, 16-way unrolled bf16 gather ------------

__global__ void aggregate(const ushort4* __restrict__ hb, const int* __restrict__ csr_ptr,
                          const int* __restrict__ csr_src, const float* __restrict__ dinv,
                          const float* __restrict__ conv_bias, float4* __restrict__ out,
                          double* __restrict__ sums, int N) {
  int wave = threadIdx.x >> 6;
  int lane = threadIdx.x & 63;
  int row = blockIdx.x * 4 + wave;
  float s1 = 0.f, s2 = 0.f;

  if (row < N) {
    float di = dinv[row];
    int b0 = csr_ptr[row], b1 = csr_ptr[row + 1];
    ushort4 self = hb[(size_t)row * 64 + lane];
    float4 acc;
    acc.x = bf2f(self.x); acc.y = bf2f(self.y);
    acc.z = bf2f(self.z); acc.w = bf2f(self.w);

    for (int e = b0; e < b1; e += 16) {
      int idx[16];
#pragma unroll
      for (int j = 0; j < 16; ++j) {
        int ee = e + j;
        idx[j] = csr_src[ee < b1 ? ee : b1 - 1];
      }
      ushort4 v[16];
#pragma unroll
      for (int j = 0; j < 16; ++j) v[j] = hb[(size_t)idx[j] * 64 + lane];
#pragma unroll
      for (int j = 0; j < 16; ++j) {
        float m = (e + j < b1) ? 1.f : 0.f;
        acc.x = fmaf(bf2f(v[j].x), m, acc.x);
        acc.y = fmaf(bf2f(v[j].y), m, acc.y);
        acc.z = fmaf(bf2f(v[j].z), m, acc.z);
        acc.w = fmaf(bf2f(v[j].w), m, acc.w);
      }
    }

    float4 b = *(const float4*)(conv_bias + lane * 4);
    acc.x = fmaf(acc.x, di, b.x);
    acc.y = fmaf(acc.y, di, b.y);
    acc.z = fmaf(acc.z, di, b.z);
    acc.w = fmaf(acc.w, di, b.w);
    out[(size_t)row * 64 + lane] = acc;
    s1 = acc.x + acc.y + acc.z + acc.w;
    s2 = acc.x * acc.x + acc.y * acc.y + acc.z * acc.z + acc.w * acc.w;
  }

  __shared__ float r1[256];
  __shared__ float r2[256];
  int t = threadIdx.x;
  r1[t] = s1;
  r2[t] = s2;
  __syncthreads();
  for (int off = 128; off > 0; off >>= 1) {
    if (t < off) { r1[t] += r1[t + off]; r2[t] += r2[t + off]; }
    __syncthreads();
  }
  if (t == 0) {
    atomicAdd(&sums[0], (double)r1[0]);
    atomicAdd(&sums[1], (double)r2[0]);
  }
}

__global__ void finalize_stats(const double* __restrict__ sums, float* __restrict__ stats,
                               double cnt) {
  double mu = sums[0] / cnt;
  double var = sums[1] / cnt - mu * mu;
  if (var < 0) var = 0;
  double sd = sqrt(var);
  stats[0] = (float)mu;
  stats[1] = (float)(1.0 / (sd + (double)EPSV));
}

__global__ void norm_prelu(float4* __restrict__ out, const float* __restrict__ stats,
                           const float* __restrict__ lw, const float* __restrict__ lb,
                           const float* __restrict__ pa, int n4) {
  int i = blockIdx.x * blockDim.x + threadIdx.x;
  if (i >= n4) return;
  float mu = stats[0];
  float inv = stats[1];
  float a = pa[0];
  int c4 = (i & 63) * 4;
  float4 w = *(const float4*)(lw + c4);
  float4 b = *(const float4*)(lb + c4);
  float4 v = out[i];
  float y0 = (v.x - mu) * inv * w.x + b.x;
  float y1 = (v.y - mu) * inv * w.y + b.y;
  float y2 = (v.z - mu) * inv * w.z + b.z;
  float y3 = (v.w - mu) * inv * w.w + b.w;
  v.x = y0 >= 0.f ? y0 : a * y0;
  v.y = y1 >= 0.f ? y1 : a * y1;
  v.z = y2 >= 0.f ? y2 : a * y2;
  v.w = y3 >= 0.f ? y3 : a * y3;
  out[i] = v;
}

// ---- launch ---------------------------------------------------------------

extern "C" void kernel_launch(void* const* d_in, const int* in_sizes, int n_in,
                              void* d_out, int out_size, void* d_ws, size_t ws_size,
                              hipStream_t stream) {
  const float* x = (const float*)d_in[0];
  const int* eidx = (const int*)d_in[1];
  const float* W = (const float*)d_in[3];
  const float* conv_bias = (const float*)d_in[4];
  const float* ln_w = (const float*)d_in[5];
  const float* ln_b = (const float*)d_in[6];
  const float* prelu_a = (const float*)d_in[7];
  float* out = (float*)d_out;

  int N = in_sizes[0] / F;
  int E = in_sizes[1] / 2;
  const int* src = eidx;
  const int* dst = eidx + E;

  char* p = (char*)d_ws;
  auto carve = [&](size_t bytes) { char* r = p; p += (bytes + 255) & ~(size_t)255; return r; };
  ushort4* hb    = (ushort4*)carve((size_t)N * 64 * sizeof(ushort4));  // bf16 h'
  unsigned short* Wb = (unsigned short*)carve((size_t)F * F * sizeof(short));
  int* deg_cnt   = (int*)carve((size_t)N * sizeof(int));
  float* dinv    = (float*)carve((size_t)N * sizeof(float));
  int* csr_ptr   = (int*)carve((size_t)(N + 1) * sizeof(int));
  int* csr_fill  = (int*)carve((size_t)N * sizeof(int));
  int* csr_src   = (int*)carve((size_t)E * sizeof(int));
  int NB = (N + 255) / 256;
  int* bsum      = (int*)carve((size_t)NB * sizeof(int));
  int* boff      = (int*)carve((size_t)NB * sizeof(int));
  double* sums   = (double*)carve(2 * sizeof(double));
  float* stats   = (float*)carve(2 * sizeof(float));

  hipMemsetAsync(deg_cnt, 0, (size_t)N * sizeof(int), stream);
  hipMemsetAsync(csr_fill, 0, (size_t)N * sizeof(int), stream);
  hipMemsetAsync(sums, 0, 2 * sizeof(double), stream);

  int eb = (E + 255) / 256;
  count_deg<<<eb, 256, 0, stream>>>(dst, deg_cnt, E);
  compute_dinv<<<NB, 256, 0, stream>>>(deg_cnt, dinv, N);
  block_sums<<<NB, 256, 0, stream>>>(deg_cnt, bsum, N);
  scan_bsums<<<1, 256, 0, stream>>>(bsum, boff, NB);
  write_csr<<<NB, 256, 0, stream>>>(deg_cnt, boff, csr_ptr, N, E);
  fill_csr<<<eb, 256, 0, stream>>>(src, dst, csr_ptr, csr_fill, csr_src, E);

  prep_W<<<(F * F) / 256, 256, 0, stream>>>(W, Wb);
  gemm_xw<<<(N + 15) / 16, 256, 0, stream>>>(x, Wb, dinv, hb, N);

  aggregate<<<(N + 3) / 4, 256, 0, stream>>>(hb, csr_ptr, csr_src, dinv,
                                             conv_bias, (float4*)out, sums, N);
  finalize_stats<<<1, 1, 0, stream>>>(sums, stats, (double)N * (double)F);
  int n4 = N * (F / 4);
  norm_prelu<<<(n4 + 255) / 256, 256, 0, stream>>>((float4*)out, stats, ln_w, ln_b, prelu_a, n4);
}

// Round 4
// 331.184 us; speedup vs baseline: 4.4632x; 1.7193x over previous
//
#include <hip/hip_runtime.h>
#include <hip/hip_bf16.h>

// GCNBlock: h' = (x@W)*dinv stored bf16 ; gather-aggregate (atomic-free stats) ;
// graph-LayerNorm ; PReLU.  N=50000, E=800000, F=256

#define F 256
#define EPSV 1e-5f

typedef __attribute__((ext_vector_type(8))) short short8;
typedef __attribute__((ext_vector_type(4))) float f32x4;

__device__ __forceinline__ unsigned short f2bf(float f) {
  union { float f; unsigned u; } v; v.f = f;
  unsigned r = v.u + 0x7fffu + ((v.u >> 16) & 1u);  // RNE
  return (unsigned short)(r >> 16);
}

__device__ __forceinline__ float bf2f(unsigned short u) {
  union { unsigned u; float f; } v; v.u = ((unsigned)u) << 16; return v.f;
}

// ---- CSR build -------------------------------------------------------------

__global__ void count_deg(const int* __restrict__ dst, int* __restrict__ deg_cnt, int E) {
  int e = blockIdx.x * blockDim.x + threadIdx.x;
  if (e < E) atomicAdd(&deg_cnt[dst[e]], 1);
}

__global__ void compute_dinv(const int* __restrict__ deg_cnt, float* __restrict__ dinv, int N) {
  int i = blockIdx.x * blockDim.x + threadIdx.x;
  if (i < N) dinv[i] = rsqrtf((float)(deg_cnt[i] + 1));  // +1 self loop
}

__global__ void block_sums(const int* __restrict__ deg_cnt, int* __restrict__ bsum, int N) {
  __shared__ int s[256];
  int t = threadIdx.x;
  int i = blockIdx.x * 256 + t;
  s[t] = (i < N) ? deg_cnt[i] : 0;
  __syncthreads();
  for (int off = 128; off > 0; off >>= 1) {
    if (t < off) s[t] += s[t + off];
    __syncthreads();
  }
  if (t == 0) bsum[blockIdx.x] = s[0];
}

__global__ void scan_bsums(const int* __restrict__ bsum, int* __restrict__ boff, int nb) {
  __shared__ int s[256];
  int t = threadIdx.x;
  int v = (t < nb) ? bsum[t] : 0;
  s[t] = v;
  __syncthreads();
  for (int off = 1; off < 256; off <<= 1) {
    int x = (t >= off) ? s[t - off] : 0;
    __syncthreads();
    s[t] += x;
    __syncthreads();
  }
  if (t < nb) boff[t] = s[t] - v;  // exclusive
}

__global__ void write_csr(const int* __restrict__ deg_cnt, const int* __restrict__ boff,
                          int* __restrict__ csr_ptr, int N, int E) {
  __shared__ int s[256];
  int t = threadIdx.x;
  int i = blockIdx.x * 256 + t;
  int v = (i < N) ? deg_cnt[i] : 0;
  s[t] = v;
  __syncthreads();
  for (int off = 1; off < 256; off <<= 1) {
    int x = (t >= off) ? s[t - off] : 0;
    __syncthreads();
    s[t] += x;
    __syncthreads();
  }
  if (i < N) csr_ptr[i] = boff[blockIdx.x] + s[t] - v;
  if (i == 0) csr_ptr[N] = E;
}

__global__ void fill_csr(const int* __restrict__ src, const int* __restrict__ dst,
                         const int* __restrict__ csr_ptr, int* __restrict__ csr_fill,
                         int* __restrict__ csr_src, int E) {
  int e = blockIdx.x * blockDim.x + threadIdx.x;
  if (e < E) {
    int d = dst[e];
    int pos = csr_ptr[d] + atomicAdd(&csr_fill[d], 1);
    csr_src[pos] = src[e];
  }
}

// ---- GEMM h' = (x @ W) * dinv[row], stored bf16 (MFMA) ---------------------

__global__ void prep_W(const float* __restrict__ W, unsigned short* __restrict__ Wb) {
  int gid = blockIdx.x * blockDim.x + threadIdx.x;  // 65536 total
  int j = gid & 7;
  int lane = (gid >> 3) & 63;
  int kc = (gid >> 9) & 7;
  int t = gid >> 12;
  int k = kc * 32 + (lane >> 4) * 8 + j;
  int n = t * 16 + (lane & 15);
  Wb[gid] = f2bf(W[k * 256 + n]);
}

// block = 256 thr = 4 waves; block handles 16 rows x 256 cols; wave w -> cols w*64..
__global__ void gemm_xw(const float* __restrict__ x, const unsigned short* __restrict__ Wb,
                        const float* __restrict__ dinv, ushort4* __restrict__ hb, int N) {
  int lane = threadIdx.x & 63;
  int wave = threadIdx.x >> 6;
  int m0 = blockIdx.x * 16;
  int q = lane >> 4;

  int row = m0 + (lane & 15);
  int rowc = row < N ? row : N - 1;

  f32x4 acc[4] = {{0,0,0,0},{0,0,0,0},{0,0,0,0},{0,0,0,0}};

  for (int kc = 0; kc < 8; ++kc) {
    int koff = kc * 32 + q * 8;
    const float4* xp = (const float4*)(x + (size_t)rowc * F + koff);
    float4 a0 = xp[0];
    float4 a1 = xp[1];
    short8 a;
    a[0] = f2bf(a0.x); a[1] = f2bf(a0.y); a[2] = f2bf(a0.z); a[3] = f2bf(a0.w);
    a[4] = f2bf(a1.x); a[5] = f2bf(a1.y); a[6] = f2bf(a1.z); a[7] = f2bf(a1.w);
#pragma unroll
    for (int tt = 0; tt < 4; ++tt) {
      const short8 b = *(const short8*)(Wb + (((wave * 4 + tt) * 8 + kc) * 64 + lane) * 8);
      acc[tt] = __builtin_amdgcn_mfma_f32_16x16x32_bf16(a, b, acc[tt], 0, 0, 0);
    }
  }

  // scale by dinv[row] and repack via LDS to coalesced bf16 stores
  __shared__ unsigned short lds[16][264];  // +8 pad breaks bank alias
  int crow = q * 4;
  int ccol = lane & 15;
#pragma unroll
  for (int rr = 0; rr < 4; ++rr) {
    int orow = m0 + crow + rr;
    float dv = (orow < N) ? dinv[orow] : 0.f;
#pragma unroll
    for (int tt = 0; tt < 4; ++tt) {
      lds[crow + rr][wave * 64 + tt * 16 + ccol] = f2bf(acc[tt][rr] * dv);
    }
  }
  __syncthreads();
  int t = threadIdx.x;
  int lrow = t >> 4;
  int grow = m0 + lrow;
  if (grow < N) {
#pragma unroll
    for (int it = 0; it < 4; ++it) {
      int c4 = (t & 15) + 16 * it;  // ushort4 index 0..63
      ushort4 u = *(const ushort4*)&lds[lrow][c4 * 4];
      hb[(size_t)grow * 64 + c4] = u;
    }
  }
}

// ---- Aggregation: one row per wave, 16-way unrolled bf16 gather ------------
// Per-block (sum, sumsq) goes to partials[blk] — NO global atomics.

__global__ void aggregate(const ushort4* __restrict__ hb, const int* __restrict__ csr_ptr,
                          const int* __restrict__ csr_src, const float* __restrict__ dinv,
                          const float* __restrict__ conv_bias, float4* __restrict__ out,
                          double2* __restrict__ partials, int N) {
  int wave = threadIdx.x >> 6;
  int lane = threadIdx.x & 63;
  int row = blockIdx.x * 4 + wave;
  float s1 = 0.f, s2 = 0.f;

  if (row < N) {
    float di = dinv[row];
    int b0 = csr_ptr[row], b1 = csr_ptr[row + 1];
    ushort4 self = hb[(size_t)row * 64 + lane];
    float4 acc;
    acc.x = bf2f(self.x); acc.y = bf2f(self.y);
    acc.z = bf2f(self.z); acc.w = bf2f(self.w);

    for (int e = b0; e < b1; e += 16) {
      int idx[16];
#pragma unroll
      for (int j = 0; j < 16; ++j) {
        int ee = e + j;
        idx[j] = csr_src[ee < b1 ? ee : b1 - 1];
      }
      ushort4 v[16];
#pragma unroll
      for (int j = 0; j < 16; ++j) v[j] = hb[(size_t)idx[j] * 64 + lane];
#pragma unroll
      for (int j = 0; j < 16; ++j) {
        float m = (e + j < b1) ? 1.f : 0.f;
        acc.x = fmaf(bf2f(v[j].x), m, acc.x);
        acc.y = fmaf(bf2f(v[j].y), m, acc.y);
        acc.z = fmaf(bf2f(v[j].z), m, acc.z);
        acc.w = fmaf(bf2f(v[j].w), m, acc.w);
      }
    }

    float4 b = *(const float4*)(conv_bias + lane * 4);
    acc.x = fmaf(acc.x, di, b.x);
    acc.y = fmaf(acc.y, di, b.y);
    acc.z = fmaf(acc.z, di, b.z);
    acc.w = fmaf(acc.w, di, b.w);
    out[(size_t)row * 64 + lane] = acc;
    s1 = acc.x + acc.y + acc.z + acc.w;
    s2 = acc.x * acc.x + acc.y * acc.y + acc.z * acc.z + acc.w * acc.w;
  }

  __shared__ float r1[256];
  __shared__ float r2[256];
  int t = threadIdx.x;
  r1[t] = s1;
  r2[t] = s2;
  __syncthreads();
  for (int off = 128; off > 0; off >>= 1) {
    if (t < off) { r1[t] += r1[t + off]; r2[t] += r2[t + off]; }
    __syncthreads();
  }
  if (t == 0) {
    double2 pp;
    pp.x = (double)r1[0];
    pp.y = (double)r2[0];
    partials[blockIdx.x] = pp;
  }
}

// single block, 1024 threads: reduce partials -> stats
__global__ void finalize_stats(const double2* __restrict__ partials, int nb,
                               float* __restrict__ stats, double cnt) {
  __shared__ double q1[1024];
  __shared__ double q2[1024];
  int t = threadIdx.x;
  double a1 = 0.0, a2 = 0.0;
  for (int i = t; i < nb; i += 1024) {
    double2 pp = partials[i];
    a1 += pp.x;
    a2 += pp.y;
  }
  q1[t] = a1;
  q2[t] = a2;
  __syncthreads();
  for (int off = 512; off > 0; off >>= 1) {
    if (t < off) { q1[t] += q1[t + off]; q2[t] += q2[t + off]; }
    __syncthreads();
  }
  if (t == 0) {
    double mu = q1[0] / cnt;
    double var = q2[0] / cnt - mu * mu;
    if (var < 0) var = 0;
    double sd = sqrt(var);
    stats[0] = (float)mu;
    stats[1] = (float)(1.0 / (sd + (double)EPSV));
  }
}

__global__ void norm_prelu(float4* __restrict__ out, const float* __restrict__ stats,
                           const float* __restrict__ lw, const float* __restrict__ lb,
                           const float* __restrict__ pa, int n4) {
  int i = blockIdx.x * blockDim.x + threadIdx.x;
  if (i >= n4) return;
  float mu = stats[0];
  float inv = stats[1];
  float a = pa[0];
  int c4 = (i & 63) * 4;
  float4 w = *(const float4*)(lw + c4);
  float4 b = *(const float4*)(lb + c4);
  float4 v = out[i];
  float y0 = (v.x - mu) * inv * w.x + b.x;
  float y1 = (v.y - mu) * inv * w.y + b.y;
  float y2 = (v.z - mu) * inv * w.z + b.z;
  float y3 = (v.w - mu) * inv * w.w + b.w;
  v.x = y0 >= 0.f ? y0 : a * y0;
  v.y = y1 >= 0.f ? y1 : a * y1;
  v.z = y2 >= 0.f ? y2 : a * y2;
  v.w = y3 >= 0.f ? y3 : a * y3;
  out[i] = v;
}

// ---- launch ---------------------------------------------------------------

extern "C" void kernel_launch(void* const* d_in, const int* in_sizes, int n_in,
                              void* d_out, int out_size, void* d_ws, size_t ws_size,
                              hipStream_t stream) {
  const float* x = (const float*)d_in[0];
  const int* eidx = (const int*)d_in[1];
  const float* W = (const float*)d_in[3];
  const float* conv_bias = (const float*)d_in[4];
  const float* ln_w = (const float*)d_in[5];
  const float* ln_b = (const float*)d_in[6];
  const float* prelu_a = (const float*)d_in[7];
  float* out = (float*)d_out;

  int N = in_sizes[0] / F;
  int E = in_sizes[1] / 2;
  const int* src = eidx;
  const int* dst = eidx + E;

  int nAggBlocks = (N + 3) / 4;

  char* p = (char*)d_ws;
  auto carve = [&](size_t bytes) { char* r = p; p += (bytes + 255) & ~(size_t)255; return r; };
  ushort4* hb    = (ushort4*)carve((size_t)N * 64 * sizeof(ushort4));  // bf16 h'
  unsigned short* Wb = (unsigned short*)carve((size_t)F * F * sizeof(short));
  int* deg_cnt   = (int*)carve((size_t)N * sizeof(int));
  float* dinv    = (float*)carve((size_t)N * sizeof(float));
  int* csr_ptr   = (int*)carve((size_t)(N + 1) * sizeof(int));
  int* csr_fill  = (int*)carve((size_t)N * sizeof(int));
  int* csr_src   = (int*)carve((size_t)E * sizeof(int));
  int NB = (N + 255) / 256;
  int* bsum      = (int*)carve((size_t)NB * sizeof(int));
  int* boff      = (int*)carve((size_t)NB * sizeof(int));
  double2* partials = (double2*)carve((size_t)nAggBlocks * sizeof(double2));
  float* stats   = (float*)carve(2 * sizeof(float));

  hipMemsetAsync(deg_cnt, 0, (size_t)N * sizeof(int), stream);
  hipMemsetAsync(csr_fill, 0, (size_t)N * sizeof(int), stream);

  int eb = (E + 255) / 256;
  count_deg<<<eb, 256, 0, stream>>>(dst, deg_cnt, E);
  compute_dinv<<<NB, 256, 0, stream>>>(deg_cnt, dinv, N);
  block_sums<<<NB, 256, 0, stream>>>(deg_cnt, bsum, N);
  scan_bsums<<<1, 256, 0, stream>>>(bsum, boff, NB);
  write_csr<<<NB, 256, 0, stream>>>(deg_cnt, boff, csr_ptr, N, E);
  fill_csr<<<eb, 256, 0, stream>>>(src, dst, csr_ptr, csr_fill, csr_src, E);

  prep_W<<<(F * F) / 256, 256, 0, stream>>>(W, Wb);
  gemm_xw<<<(N + 15) / 16, 256, 0, stream>>>(x, Wb, dinv, hb, N);

  aggregate<<<nAggBlocks, 256, 0, stream>>>(hb, csr_ptr, csr_src, dinv,
                                            conv_bias, (float4*)out, partials, N);
  finalize_stats<<<1, 1024, 0, stream>>>(partials, nAggBlocks, stats,
                                         (double)N * (double)F);
  int n4 = N * (F / 4);
  norm_prelu<<<(n4 + 255) / 256, 256, 0, stream>>>((float4*)out, stats, ln_w, ln_b, prelu_a, n4);
}